// Round 10
// baseline (132.954 us; speedup 1.0000x reference)
//
#include <hip/hip_runtime.h>

// R15: FUSED ZERO-BARRIER. R14 == R13 (127.4/127.5) closed the issue-pressure
// axis. Last identified non-stream term: the split structure's serialized
// {table-kernel dispatch -> complete -> main dispatch} = ~4-6us dead window
// (param latency chain + MLP + 2 launch overheads) with zero streaming.
// Fix: fuse the prologue back IN R13's ZERO-SYNC FORM — each wave computes
// MLP->knots->de Boor into its own 528B LDS region, NO __syncthreads anywhere
// (same-wave LDS ordering, proven R6/R13), params issued before the x
// prefetch (R6: small-vmcnt wait), prologue hides under the x stream.
// Phase-2 loop, NT stores, 2-deep prefetch, 2048 persistent blocks: byte-
// identical to R14. Cost: ~800 redundant VALU inst/wave (~5us/SIMD integrated,
// hidden under the 16-30us memory window). Saved: 2 dispatches + table-kernel
// serial runtime.
// Decision rule: win -> dispatch overhead was the slack; neutral/regress ->
// split optimal, ALL axes exhausted, declare roofline (stream already at
// ~70% of the m13 copy ceiling with 25 VALU/elem + LDS gather on top).

#define CHUNKS 8

typedef float floatx4 __attribute__((ext_vector_type(4)));

__global__ __launch_bounds__(256) void nsff_fused_nb_kernel(
    const float4* __restrict__ x, float4* __restrict__ out,
    const float* __restrict__ a,
    const float* __restrict__ W1, const float* __restrict__ b1,
    const float* __restrict__ W2, const float* __restrict__ b2,
    const float* __restrict__ Ww, const float* __restrict__ bw,
    const float* __restrict__ Wk, const float* __restrict__ bk) {
    // Per-wave private LDS regions: no cross-wave traffic, no barriers.
    __shared__ float net1s[4][32];
    __shared__ float net2s[4][32];
    __shared__ float w9ss[4][9];
    __shared__ float krawss[4][7];
    __shared__ float tshs[4][14];
    __shared__ float w10ss[4][10];
    __shared__ float tblws[4][28];

    const int tid = threadIdx.x;
    const int wid = tid >> 6;
    const int lane = tid & 63;

    const int stride = gridDim.x * 256;   // 2048*256 = 524288 float4s
    const int base = blockIdx.x * 256 + tid;

    // Stage-1 params FIRST in the VMEM queue (R6): waiting on them later is a
    // small-N vmcnt; the x loads behind them keep streaming.
    float a0 = 0.f, w1v = 0.f, b1v = 0.f;
    if (lane < 32) { a0 = a[0]; w1v = W1[lane]; b1v = b1[lane]; }

    // Prime the x pipeline: 2 loads in flight before the prologue.
    float4 cur = x[base];
    float4 nxt = x[base + stride];
    asm volatile("" ::: "memory");  // pin load issue above the prologue

    // ---- Prologue, per wave, zero barriers (same-wave LDS ops are ordered
    //      at the LDS; exec-masked sub-wave phases run in program order) ----
    if (lane < 32) net1s[wid][lane] = sinf(a0 * w1v + b1v);
    if (lane < 32) {
        float s = b2[lane];
#pragma unroll 16
        for (int j = 0; j < 32; ++j) s += net1s[wid][j] * W2[j * 32 + lane];
        net2s[wid][lane] = sinf(s);
    }
    if (lane < 9) {
        float s = bw[lane];
#pragma unroll
        for (int j = 0; j < 32; ++j) s += net2s[wid][j] * Ww[j * 9 + lane];
        w9ss[wid][lane] = s;
    } else if (lane >= 16 && lane < 23) {
        const int i = lane - 16;
        float s = bk[i];
#pragma unroll
        for (int j = 0; j < 32; ++j) s += net2s[wid][j] * Wk[j * 7 + i];
        krawss[wid][i] = s;
    }
    if (lane == 0) {
        // softmax (max-subtracted) -> cumsum -> knot vector
        float mx = krawss[wid][0];
        for (int i = 1; i < 7; ++i) mx = fmaxf(mx, krawss[wid][i]);
        float e[7], sum = 0.f;
        for (int i = 0; i < 7; ++i) { e[i] = expf(krawss[wid][i] - mx); sum += e[i]; }
        const float invsum = 1.f / sum;
        tshs[wid][0] = tshs[wid][1] = tshs[wid][2] = tshs[wid][3] = 0.f;
        float cum = 0.f;
        for (int i = 0; i < 7; ++i) { cum += e[i] * invsum; tshs[wid][4 + i] = cum; }
        tshs[wid][11] = tshs[wid][12] = tshs[wid][13] = 1.f;
        w10ss[wid][0] = 0.f;
        for (int i = 0; i < 9; ++i) w10ss[wid][1 + i] = w9ss[wid][i];
    }
    if (lane < 7) {
        // Symbolic de Boor expansion for interval k = lane+3 in s = xp - t[k]
        // (centered form: absolute-xp would amplify rounding by ~1/h^3).
        const int k = lane + 3;
        float d[4][4];
        for (int j = 0; j < 4; ++j) {
            d[j][0] = w10ss[wid][k - 3 + j];
            d[j][1] = 0.f; d[j][2] = 0.f; d[j][3] = 0.f;
        }
        for (int r = 1; r <= 3; ++r) {
            for (int j = 3; j >= r; --j) {
                const float t0 = tshs[wid][j + k - 3];
                const float t1 = tshs[wid][j + 1 + k - r];
                const float den = t1 - t0;
                const float invd = (den != 0.f) ? (1.f / den) : 0.f;  // no NaN from degenerate intervals
                const float a0_ = (tshs[wid][k] - t0) * invd;
                float nd[4];
                for (int i = 0; i < 4; ++i) nd[i] = d[j - 1][i] + a0_ * (d[j][i] - d[j - 1][i]);
                for (int i = 0; i < 3; ++i) nd[i + 1] += invd * (d[j][i] - d[j - 1][i]);
                for (int i = 0; i < 4; ++i) d[j][i] = nd[i];
            }
        }
        tblws[wid][4 * lane + 0] = d[3][0];
        tblws[wid][4 * lane + 1] = d[3][1];
        tblws[wid][4 * lane + 2] = d[3][2];
        tblws[wid][4 * lane + 3] = d[3][3];
    }

    const float4* tbl = reinterpret_cast<const float4*>(tblws[wid]);
    // Decision knots: wave-uniform LDS address -> broadcast reads; values
    // written by lane 0 above (same-wave ordering, no barrier needed).
    float cs[6];
#pragma unroll
    for (int i = 0; i < 6; ++i) cs[i] = tshs[wid][4 + i];

    // ---- Phase 2: persistent pipelined stream (byte-identical to R14) ----
#pragma unroll
    for (int it = 0; it < CHUNKS; ++it) {
        float4 fol;
        if (it + 2 < CHUNKS) fol = x[base + (it + 2) * stride];

        floatx4 r;
#pragma unroll
        for (int c = 0; c < 4; ++c) {
            const float xi = (&cur.x)[c];
            const float xp = __builtin_amdgcn_fmed3f(
                xi * 0.57735026918962576f, 0.0f, 0.9999f);  // v_med3 clamp
            int kk = 0;
            float tk = 0.f;
#pragma unroll
            for (int i = 0; i < 6; ++i) {
                if (xp >= cs[i]) { kk = i + 1; tk = cs[i]; }
            }
            const float s = xp - tk;
            const float4 cf = tbl[kk];  // broadcast-heavy, conflict-free (measured 0)
            r[c] = fmaf(fmaf(fmaf(cf.w, s, cf.z), s, cf.y), s, cf.x);
        }
        __builtin_nontemporal_store(
            r, reinterpret_cast<floatx4*>(&out[base + it * stride]));  // NT stores (R9)

        cur = nxt;
        nxt = fol;
    }
}

extern "C" void kernel_launch(void* const* d_in, const int* in_sizes, int n_in,
                              void* d_out, int out_size, void* d_ws, size_t ws_size,
                              hipStream_t stream) {
    const float* x  = (const float*)d_in[0];
    const float* a  = (const float*)d_in[1];
    const float* W1 = (const float*)d_in[2];
    const float* b1 = (const float*)d_in[3];
    const float* W2 = (const float*)d_in[4];
    const float* b2 = (const float*)d_in[5];
    const float* Ww = (const float*)d_in[6];
    const float* bw = (const float*)d_in[7];
    const float* Wk = (const float*)d_in[8];
    const float* bk = (const float*)d_in[9];
    float* out = (float*)d_out;

    const int n4 = out_size / 4;            // 256^3/4 = 4,194,304
    const int blocks = n4 / (256 * CHUNKS); // = 2048 persistent (8/CU)

    nsff_fused_nb_kernel<<<blocks, 256, 0, stream>>>((const float4*)x,
                                                     (float4*)out, a, W1, b1,
                                                     W2, b2, Ww, bw, Wk, bk);
}

// Round 11
// 127.437 us; speedup vs baseline: 1.0433x; 1.0433x over previous
//
#include <hip/hip_runtime.h>

// FINAL (revert to R14, the measured optimum: 127.4us total).
// Session ladder: 134.6 (R5 baseline) -> 129.1 (R11: ITERS=2 churn) ->
// 127.5 (R13: zero-sync per-wave tables) -> 127.4 (R14: persistent pipeline).
// Falsified/exhausted axes: instruction scheduling (R5/6/7 identical),
// cache hints (R4 NT-loads regress; R9 NT-stores ~neutral, kept),
// prologue placement (R10 split == fused; R15 zero-barrier fusion REGRESSED
// 133.0 -> split is optimal), r/w phasing (R6==R7), work granularity
// (R11/R12: ITERS 8/2/1 -> 132/129.1/135.8, optimum at 2; CHUNKS=8 persistent
// == ITERS=2 churn), sync elimination (R13 win), issue pressure (R14==R13).
// Main kernel ~30us = 132MB mixed r/w at ~4.4TB/s (~70% of the 6.3TB/s copy
// ceiling) with 25 VALU/elem + LDS gather on top. Empirical roofline.

#define CHUNKS 8

typedef float floatx4 __attribute__((ext_vector_type(4)));

// ---------------------------------------------------------------------------
// Kernel 1: one wave computes the tiny MLP -> knot vector -> per-interval
// cubic coefficients (centered at s = xp - t[k]; absolute-xp form would
// amplify rounding by ~1/h^3 and blow the threshold) and writes to workspace:
//   ws[0..27]  = 7 x float4 coefficient table
//   ws[28..33] = 6 interior decision knots (t4..t9)
// ---------------------------------------------------------------------------
__global__ __launch_bounds__(64) void nsff_table_kernel(
    float* __restrict__ ws,
    const float* __restrict__ a,
    const float* __restrict__ W1, const float* __restrict__ b1,
    const float* __restrict__ W2, const float* __restrict__ b2,
    const float* __restrict__ Ww, const float* __restrict__ bw,
    const float* __restrict__ Wk, const float* __restrict__ bk) {
    __shared__ float net1[32];
    __shared__ float net2[32];
    __shared__ float w9s[9];
    __shared__ float kraws[7];
    __shared__ float tsh[14];
    __shared__ float w10s[10];

    const int tid = threadIdx.x;  // single wave: same-wave LDS ops are ordered,
                                  // no barriers needed (R6-proven structure)
    if (tid < 32) net1[tid] = sinf(a[0] * W1[tid] + b1[tid]);
    if (tid < 32) {
        float s = b2[tid];
#pragma unroll 16
        for (int j = 0; j < 32; ++j) s += net1[j] * W2[j * 32 + tid];
        net2[tid] = sinf(s);
    }
    if (tid < 9) {
        float s = bw[tid];
#pragma unroll
        for (int j = 0; j < 32; ++j) s += net2[j] * Ww[j * 9 + tid];
        w9s[tid] = s;
    } else if (tid >= 16 && tid < 23) {
        const int i = tid - 16;
        float s = bk[i];
#pragma unroll
        for (int j = 0; j < 32; ++j) s += net2[j] * Wk[j * 7 + i];
        kraws[i] = s;
    }
    if (tid == 0) {
        // softmax (max-subtracted) -> cumsum -> knot vector
        float mx = kraws[0];
        for (int i = 1; i < 7; ++i) mx = fmaxf(mx, kraws[i]);
        float e[7], sum = 0.f;
        for (int i = 0; i < 7; ++i) { e[i] = expf(kraws[i] - mx); sum += e[i]; }
        const float invsum = 1.f / sum;
        tsh[0] = tsh[1] = tsh[2] = tsh[3] = 0.f;
        float cs = 0.f;
        for (int i = 0; i < 7; ++i) { cs += e[i] * invsum; tsh[4 + i] = cs; }
        tsh[11] = tsh[12] = tsh[13] = 1.f;
        w10s[0] = 0.f;
        for (int i = 0; i < 9; ++i) w10s[1 + i] = w9s[i];
        for (int i = 0; i < 6; ++i) ws[28 + i] = tsh[4 + i];  // decision knots
    }
    if (tid < 7) {
        // Symbolic de Boor expansion for interval k = tid+3 in s = xp - t[k].
        const int k = tid + 3;
        float d[4][4];
        for (int j = 0; j < 4; ++j) {
            d[j][0] = w10s[k - 3 + j];
            d[j][1] = 0.f; d[j][2] = 0.f; d[j][3] = 0.f;
        }
        for (int r = 1; r <= 3; ++r) {
            for (int j = 3; j >= r; --j) {
                const float t0 = tsh[j + k - 3];
                const float t1 = tsh[j + 1 + k - r];
                const float den = t1 - t0;
                const float invd = (den != 0.f) ? (1.f / den) : 0.f;  // no NaN from degenerate intervals
                const float a0_ = (tsh[k] - t0) * invd;
                float nd[4];
                for (int i = 0; i < 4; ++i) nd[i] = d[j - 1][i] + a0_ * (d[j][i] - d[j - 1][i]);
                for (int i = 0; i < 3; ++i) nd[i + 1] += invd * (d[j][i] - d[j - 1][i]);
                for (int i = 0; i < 4; ++i) d[j][i] = nd[i];
            }
        }
        ws[4 * tid + 0] = d[3][0];
        ws[4 * tid + 1] = d[3][1];
        ws[4 * tid + 2] = d[3][2];
        ws[4 * tid + 3] = d[3][3];
    }
}

// ---------------------------------------------------------------------------
// Kernel 2: persistent pipelined streaming map. No barrier; per-wave LDS
// table (R13); 2-deep prefetch loop -> continuous per-wave load issue.
// ---------------------------------------------------------------------------
__global__ __launch_bounds__(256) void nsff_main_kernel(
    const float4* __restrict__ x, float4* __restrict__ out,
    const float* __restrict__ ws) {
    __shared__ float tblw[4 * 28];  // one 7-float4 table copy PER WAVE

    const int tid = threadIdx.x;
    const int wid = tid >> 6;
    const int lane = tid & 63;

    const int stride = gridDim.x * 256;       // 2048*256 = 524288 float4s
    const int base = blockIdx.x * 256 + tid;

    // Prime the pipeline: 2 loads in flight before any compute.
    float4 cur = x[base];
    float4 nxt = x[base + stride];

    // Per-wave table copy: lanes 0-27 each stage one dword. Same-wave
    // ds_write -> ds_read is ordered at the LDS: NO block barrier needed.
    if (lane < 28) tblw[wid * 28 + lane] = ws[lane];
    const float4* tbl = reinterpret_cast<const float4*>(&tblw[wid * 28]);

    // Knots: thread-uniform address -> s_load SGPR broadcast (no LDS).
    float cs[6];
#pragma unroll
    for (int i = 0; i < 6; ++i) cs[i] = ws[28 + i];

#pragma unroll
    for (int it = 0; it < CHUNKS; ++it) {
        // Issue chunk it+2's load NOW; it lands while we compute chunk it.
        float4 fol;
        if (it + 2 < CHUNKS) fol = x[base + (it + 2) * stride];

        floatx4 r;
#pragma unroll
        for (int c = 0; c < 4; ++c) {
            const float xi = (&cur.x)[c];
            const float xp = __builtin_amdgcn_fmed3f(
                xi * 0.57735026918962576f, 0.0f, 0.9999f);  // v_med3 clamp
            int kk = 0;
            float tk = 0.f;
#pragma unroll
            for (int i = 0; i < 6; ++i) {
                if (xp >= cs[i]) { kk = i + 1; tk = cs[i]; }
            }
            const float s = xp - tk;
            const float4 cf = tbl[kk];  // broadcast-heavy, conflict-free (measured 0)
            r[c] = fmaf(fmaf(fmaf(cf.w, s, cf.z), s, cf.y), s, cf.x);
        }
        __builtin_nontemporal_store(
            r, reinterpret_cast<floatx4*>(&out[base + it * stride]));  // NT stores (R9)

        cur = nxt;
        nxt = fol;
    }
}

// ---------------------------------------------------------------------------
// Fallback: fused single-kernel (used only if ws_size is too small).
// ---------------------------------------------------------------------------
__global__ __launch_bounds__(256) void nsff_fused_kernel(
    const float4* __restrict__ x, float4* __restrict__ out,
    const float* __restrict__ a,
    const float* __restrict__ W1, const float* __restrict__ b1,
    const float* __restrict__ W2, const float* __restrict__ b2,
    const float* __restrict__ Ww, const float* __restrict__ bw,
    const float* __restrict__ Wk, const float* __restrict__ bk) {
    __shared__ float net1[32];
    __shared__ float net2[32];
    __shared__ float w9s[9];
    __shared__ float kraws[7];
    __shared__ float tsh[14];
    __shared__ float w10s[10];
    __shared__ float4 tbl[7];
    __shared__ float csh[6];

    const int tid = threadIdx.x;
    const int stride = gridDim.x * 256;
    const int base = blockIdx.x * 256 + tid;

    float a0 = 0.f, w1v = 0.f, b1v = 0.f;
    if (tid < 32) { a0 = a[0]; w1v = W1[tid]; b1v = b1[tid]; }

    float4 xv[CHUNKS];
#pragma unroll
    for (int it = 0; it < CHUNKS; ++it) xv[it] = x[base + it * stride];
    asm volatile("" ::: "memory");

    if (tid < 32) net1[tid] = sinf(a0 * w1v + b1v);
    if (tid < 32) {
        float s = b2[tid];
#pragma unroll 16
        for (int j = 0; j < 32; ++j) s += net1[j] * W2[j * 32 + tid];
        net2[tid] = sinf(s);
    }
    if (tid < 9) {
        float s = bw[tid];
#pragma unroll
        for (int j = 0; j < 32; ++j) s += net2[j] * Ww[j * 9 + tid];
        w9s[tid] = s;
    } else if (tid >= 16 && tid < 23) {
        const int i = tid - 16;
        float s = bk[i];
#pragma unroll
        for (int j = 0; j < 32; ++j) s += net2[j] * Wk[j * 7 + i];
        kraws[i] = s;
    }
    if (tid == 0) {
        float mx = kraws[0];
        for (int i = 1; i < 7; ++i) mx = fmaxf(mx, kraws[i]);
        float e[7], sum = 0.f;
        for (int i = 0; i < 7; ++i) { e[i] = expf(kraws[i] - mx); sum += e[i]; }
        const float invsum = 1.f / sum;
        tsh[0] = tsh[1] = tsh[2] = tsh[3] = 0.f;
        float cs = 0.f;
        for (int i = 0; i < 7; ++i) { cs += e[i] * invsum; tsh[4 + i] = cs; }
        tsh[11] = tsh[12] = tsh[13] = 1.f;
        w10s[0] = 0.f;
        for (int i = 0; i < 9; ++i) w10s[1 + i] = w9s[i];
        for (int i = 0; i < 6; ++i) csh[i] = tsh[4 + i];
    }
    if (tid < 7) {
        const int k = tid + 3;
        float d[4][4];
        for (int j = 0; j < 4; ++j) {
            d[j][0] = w10s[k - 3 + j];
            d[j][1] = 0.f; d[j][2] = 0.f; d[j][3] = 0.f;
        }
        for (int r = 1; r <= 3; ++r) {
            for (int j = 3; j >= r; --j) {
                const float t0 = tsh[j + k - 3];
                const float t1 = tsh[j + 1 + k - r];
                const float den = t1 - t0;
                const float invd = (den != 0.f) ? (1.f / den) : 0.f;
                const float a0_ = (tsh[k] - t0) * invd;
                float nd[4];
                for (int i = 0; i < 4; ++i) nd[i] = d[j - 1][i] + a0_ * (d[j][i] - d[j - 1][i]);
                for (int i = 0; i < 3; ++i) nd[i + 1] += invd * (d[j][i] - d[j - 1][i]);
                for (int i = 0; i < 4; ++i) d[j][i] = nd[i];
            }
        }
        tbl[tid] = make_float4(d[3][0], d[3][1], d[3][2], d[3][3]);
    }
    __syncthreads();

    float cs[6];
#pragma unroll
    for (int i = 0; i < 6; ++i) cs[i] = csh[i];

#pragma unroll
    for (int it = 0; it < CHUNKS; ++it) {
        floatx4 r;
#pragma unroll
        for (int c = 0; c < 4; ++c) {
            const float xi = (&xv[it].x)[c];
            const float xp = __builtin_amdgcn_fmed3f(
                xi * 0.57735026918962576f, 0.0f, 0.9999f);
            int kk = 0;
            float tk = 0.f;
#pragma unroll
            for (int i = 0; i < 6; ++i) {
                if (xp >= cs[i]) { kk = i + 1; tk = cs[i]; }
            }
            const float s = xp - tk;
            const float4 cf = tbl[kk];
            r[c] = fmaf(fmaf(fmaf(cf.w, s, cf.z), s, cf.y), s, cf.x);
        }
        __builtin_nontemporal_store(
            r, reinterpret_cast<floatx4*>(&out[base + it * stride]));
    }
}

extern "C" void kernel_launch(void* const* d_in, const int* in_sizes, int n_in,
                              void* d_out, int out_size, void* d_ws, size_t ws_size,
                              hipStream_t stream) {
    const float* x  = (const float*)d_in[0];
    const float* a  = (const float*)d_in[1];
    const float* W1 = (const float*)d_in[2];
    const float* b1 = (const float*)d_in[3];
    const float* W2 = (const float*)d_in[4];
    const float* b2 = (const float*)d_in[5];
    const float* Ww = (const float*)d_in[6];
    const float* bw = (const float*)d_in[7];
    const float* Wk = (const float*)d_in[8];
    const float* bk = (const float*)d_in[9];
    float* out = (float*)d_out;

    const int n4 = out_size / 4;            // 256^3/4 = 4,194,304
    const int blocks = n4 / (256 * CHUNKS); // = 2048 persistent (8/CU)

    if (d_ws != nullptr && ws_size >= 34 * sizeof(float)) {
        float* ws = (float*)d_ws;
        nsff_table_kernel<<<1, 64, 0, stream>>>(ws, a, W1, b1, W2, b2,
                                                Ww, bw, Wk, bk);
        nsff_main_kernel<<<blocks, 256, 0, stream>>>((const float4*)x,
                                                     (float4*)out, ws);
    } else {
        nsff_fused_kernel<<<blocks, 256, 0, stream>>>((const float4*)x,
                                                      (float4*)out, a, W1, b1,
                                                      W2, b2, Ww, bw, Wk, bk);
    }
}